// Round 11
// baseline (265.516 us; speedup 1.0000x reference)
//
#include <hip/hip_runtime.h>
#include <stdint.h>

#define NB 4
#define NC 256
#define NCI 128
#define NN 4096

typedef __attribute__((ext_vector_type(8))) short short8;
typedef __attribute__((ext_vector_type(4))) float f32x4;

__device__ __forceinline__ float bf2f(unsigned short u) {
    union { unsigned int i; float f; } v; v.i = ((unsigned int)u) << 16; return v.f;
}
__device__ __forceinline__ unsigned short f2bf(float f) {
    union { unsigned int i; float f; } v; v.f = f;
    unsigned int b = v.i;
    b += 0x7FFFu + ((b >> 16) & 1u);   // RNE
    return (unsigned short)(b >> 16);
}

// ---------------------------------------------------------------- sentinel fill
__global__ void k_fill(float* __restrict__ p, float v, int n) {
    int i = blockIdx.x * blockDim.x + threadIdx.x;
    if (i < n) p[i] = v;
}

// ---------------------------------------------------------------- K0: weight split/convert
__global__ __launch_bounds__(256) void k_split(
    const float* __restrict__ Wt, const float* __restrict__ Wp,
    const float* __restrict__ Wg, const float* __restrict__ Wo,
    unsigned short* __restrict__ wbuf) {
    const float LOG2E = 1.4426950408889634f;
    int m = blockIdx.y;
    int i = blockIdx.x * 256 + threadIdx.x;
    if (m == 0) {
        float v = Wt[i] * LOG2E;
        unsigned short h = f2bf(v);
        wbuf[i] = h;
        wbuf[32768 + i] = f2bf(v - bf2f(h));
    } else if (m == 1) {
        float v = Wp[i];
        unsigned short h = f2bf(v);
        wbuf[65536 + i] = h;
        wbuf[98304 + i] = f2bf(v - bf2f(h));
    } else if (m == 2) {
        wbuf[131072 + i] = f2bf(Wg[i]);
    } else {
        wbuf[163840 + i] = f2bf(Wo[i]);
    }
}

// ---------------------------------------------------------------- K1: phi (hi/lo) + g projections
__global__ __launch_bounds__(256, 2) void k_qkv2(
    const float* __restrict__ x,
    const unsigned short* __restrict__ WpH, const unsigned short* __restrict__ WpL,
    const unsigned short* __restrict__ WgH,
    const float* __restrict__ bp, const float* __restrict__ bg,
    unsigned short* __restrict__ phiH, unsigned short* __restrict__ phiL,
    unsigned short* __restrict__ gout) {
    __shared__ __align__(16) unsigned short sXh[32 * 72];
    __shared__ __align__(16) unsigned short sXl[32 * 72];
    const int b = blockIdx.y, n0 = blockIdx.x * 32;
    const int tid = threadIdx.x, lane = tid & 63, wave = tid >> 6;
    const int col = lane & 15, quad = lane >> 4;
    const int wm = wave * 32;

    f32x4 accP[2][2], accG[2][2];
#pragma unroll
    for (int i = 0; i < 2; i++)
#pragma unroll
        for (int j = 0; j < 2; j++)
#pragma unroll
            for (int e = 0; e < 4; e++) { accP[i][j][e] = 0.f; accG[i][j][e] = 0.f; }

    for (int c0 = 0; c0 < NC; c0 += 64) {
        __syncthreads();
        short8 ah[2][2], al[2][2], ag[2][2];
#pragma unroll
        for (int ks = 0; ks < 2; ks++)
#pragma unroll
            for (int i = 0; i < 2; i++) {
                size_t w = (size_t)(wm + i * 16 + col) * NC + c0 + ks * 32 + quad * 8;
                ah[ks][i] = *(const short8*)&WpH[w];
                al[ks][i] = *(const short8*)&WpL[w];
                ag[ks][i] = *(const short8*)&WgH[w];
            }
        {
            int cp = tid >> 3, n4 = (tid & 7) * 4;
            const float* xp = x + ((size_t)(b * NC + c0 + 2 * cp)) * NN + n0 + n4;
            float4 a = *(const float4*)xp;
            float4 c = *(const float4*)(xp + NN);
            float av[4] = { a.x, a.y, a.z, a.w };
            float cv[4] = { c.x, c.y, c.z, c.w };
#pragma unroll
            for (int j = 0; j < 4; j++) {
                unsigned short ha = f2bf(av[j]), hc = f2bf(cv[j]);
                unsigned short la = f2bf(av[j] - bf2f(ha)), lc = f2bf(cv[j] - bf2f(hc));
                *(unsigned int*)&sXh[(n4 + j) * 72 + 2 * cp] =
                    (unsigned int)ha | ((unsigned int)hc << 16);
                *(unsigned int*)&sXl[(n4 + j) * 72 + 2 * cp] =
                    (unsigned int)la | ((unsigned int)lc << 16);
            }
        }
        __syncthreads();
#pragma unroll
        for (int ks = 0; ks < 2; ks++)
#pragma unroll
            for (int j = 0; j < 2; j++) {
                short8 bh = *(const short8*)&sXh[(j * 16 + col) * 72 + ks * 32 + quad * 8];
                short8 bl = *(const short8*)&sXl[(j * 16 + col) * 72 + ks * 32 + quad * 8];
#pragma unroll
                for (int i = 0; i < 2; i++) {
                    accP[i][j] = __builtin_amdgcn_mfma_f32_16x16x32_bf16(ah[ks][i], bh, accP[i][j], 0, 0, 0);
                    accP[i][j] = __builtin_amdgcn_mfma_f32_16x16x32_bf16(ah[ks][i], bl, accP[i][j], 0, 0, 0);
                    accP[i][j] = __builtin_amdgcn_mfma_f32_16x16x32_bf16(al[ks][i], bh, accP[i][j], 0, 0, 0);
                    accG[i][j] = __builtin_amdgcn_mfma_f32_16x16x32_bf16(ag[ks][i], bh, accG[i][j], 0, 0, 0);
                }
            }
    }
#pragma unroll
    for (int i = 0; i < 2; i++) {
        int mrow = wm + i * 16 + quad * 4;
#pragma unroll
        for (int j = 0; j < 2; j++) {
            int n = n0 + j * 16 + col;
            unsigned short h[4], l[4];
#pragma unroll
            for (int e = 0; e < 4; e++) {
                float v = accP[i][j][e] + bp[mrow + e];
                h[e] = f2bf(v);
                l[e] = f2bf(v - bf2f(h[e]));
            }
            uint2 hv, lv;
            hv.x = (unsigned int)h[0] | ((unsigned int)h[1] << 16);
            hv.y = (unsigned int)h[2] | ((unsigned int)h[3] << 16);
            lv.x = (unsigned int)l[0] | ((unsigned int)l[1] << 16);
            lv.y = (unsigned int)l[2] | ((unsigned int)l[3] << 16);
            *(uint2*)&phiH[((size_t)(b * NN + n)) * NCI + mrow] = hv;
            *(uint2*)&phiL[((size_t)(b * NN + n)) * NCI + mrow] = lv;
#pragma unroll
            for (int r = 0; r < 4; r++)
                gout[((size_t)(b * NCI + mrow + r)) * NN + n] = f2bf(accG[i][j][r] + bg[mrow + r]);
        }
    }
}

// ---------------------------------------------------------------- K2: fused attention, 16 waves
// Block: 1024 threads, batch b, 64 queries. QK wave (qg,kq): 16 q x 16-key
// quarter (halves per-wave phi reads; 4 waves/SIMD hide latency). PV wave
// (ct2,qt): 32 c x 16 q. li merged across kq partials at the end.
__global__ __launch_bounds__(1024, 4) void k_attn(
    const float* __restrict__ x,
    const unsigned short* __restrict__ WtH, const unsigned short* __restrict__ WtL,
    const float* __restrict__ bt,
    const unsigned short* __restrict__ phiH, const unsigned short* __restrict__ phiL,
    const unsigned short* __restrict__ gmat,
    const unsigned short* __restrict__ WoH, const float* __restrict__ bo,
    float* __restrict__ y) {
    const float LOG2E = 1.4426950408889634f;
    __shared__ __align__(16) char smem[90112];
    // prologue regions
    unsigned short* sWth = (unsigned short*)(smem);            // [128 ci][72]
    unsigned short* sWtl = (unsigned short*)(smem + 18432);
    unsigned short* sXh  = (unsigned short*)(smem + 36864);    // [64 n][72]
    unsigned short* sXl  = (unsigned short*)(smem + 46080);
    unsigned short* sThH = (unsigned short*)(smem + 55296);    // [64 q][136]
    unsigned short* sThL = (unsigned short*)(smem + 72704);
    // main regions (overlay prologue; sTh dead once qh/ql in regs)
    unsigned short* sPhiH = (unsigned short*)(smem);           // [64 m][136]
    unsigned short* sPhiL = (unsigned short*)(smem + 17408);
    unsigned short* sG    = (unsigned short*)(smem + 34816);   // [128 c][72]
    unsigned short* sPall = (unsigned short*)(smem + 53248);   // [4 qg][16 q][72]
    float* sLi            = (float*)(smem + 62464);            // [16 waves][16 q]
    // epilogue regions
    unsigned short* sO    = (unsigned short*)(smem);           // [64 q][136]
    unsigned short* sWo   = (unsigned short*)(smem + 17408);   // [256 o][136]

    const int id = blockIdx.x;
    const int xcd = id & 7, slot = id >> 3;
    const int b = xcd >> 1;
    const int n0 = (slot * 2 + (xcd & 1)) * 64;

    const int tid = threadIdx.x, lane = tid & 63, wave = tid >> 6;  // 0..15
    const int col = lane & 15, quad = lane >> 4;
    const int qg = wave >> 2, kq = wave & 3;   // QK assignment
    const int qt = wave & 3, ct2 = wave >> 2;  // PV assignment

    // ---------------- prologue: theta (log2e-scaled), f32-grade split
    f32x4 th[2];
#pragma unroll
    for (int j = 0; j < 2; j++)
#pragma unroll
        for (int e = 0; e < 4; e++) th[j][e] = 0.f;
    const int wci = (wave & 7) * 16, qp = wave >> 3;

    for (int c0 = 0; c0 < NC; c0 += 64) {
        if (tid < 512) {   // waves 0-7: x transpose-split (64 c x 64 n)
            int cp = tid >> 4, n4 = (tid & 15) * 4;
            const float* xp = x + ((size_t)(b * NC + c0 + 2 * cp)) * NN + n0 + n4;
            float4 a = *(const float4*)xp;
            float4 c = *(const float4*)(xp + NN);
            float av[4] = { a.x, a.y, a.z, a.w };
            float cv[4] = { c.x, c.y, c.z, c.w };
#pragma unroll
            for (int j = 0; j < 4; j++) {
                unsigned short ha = f2bf(av[j]), hc = f2bf(cv[j]);
                unsigned short la = f2bf(av[j] - bf2f(ha)), lc = f2bf(cv[j] - bf2f(hc));
                *(unsigned int*)&sXh[(n4 + j) * 72 + 2 * cp] =
                    (unsigned int)ha | ((unsigned int)hc << 16);
                *(unsigned int*)&sXl[(n4 + j) * 72 + 2 * cp] =
                    (unsigned int)la | ((unsigned int)lc << 16);
            }
        } else {           // waves 8-15: Wt tiles [128 ci][64 c]
            int t = tid - 512;
#pragma unroll
            for (int i = 0; i < 2; i++) {
                int idx = t + i * 512;
                int row = idx >> 3, seg = idx & 7;
                *(uint4*)&sWth[row * 72 + seg * 8] =
                    *(const uint4*)&WtH[(size_t)row * NC + c0 + seg * 8];
                *(uint4*)&sWtl[row * 72 + seg * 8] =
                    *(const uint4*)&WtL[(size_t)row * NC + c0 + seg * 8];
            }
        }
        __syncthreads();
#pragma unroll
        for (int ks = 0; ks < 2; ks++) {
            short8 ah = *(const short8*)&sWth[(wci + col) * 72 + ks * 32 + quad * 8];
            short8 al = *(const short8*)&sWtl[(wci + col) * 72 + ks * 32 + quad * 8];
#pragma unroll
            for (int j = 0; j < 2; j++) {
                int qrow = qp * 32 + j * 16 + col;
                short8 bh = *(const short8*)&sXh[qrow * 72 + ks * 32 + quad * 8];
                short8 bl = *(const short8*)&sXl[qrow * 72 + ks * 32 + quad * 8];
                th[j] = __builtin_amdgcn_mfma_f32_16x16x32_bf16(ah, bh, th[j], 0, 0, 0);
                th[j] = __builtin_amdgcn_mfma_f32_16x16x32_bf16(ah, bl, th[j], 0, 0, 0);
                th[j] = __builtin_amdgcn_mfma_f32_16x16x32_bf16(al, bh, th[j], 0, 0, 0);
            }
        }
        __syncthreads();
    }
    {
        int ci = wci + quad * 4;
#pragma unroll
        for (int j = 0; j < 2; j++) {
            int q = qp * 32 + j * 16 + col;
            unsigned short h[4], l[4];
#pragma unroll
            for (int e = 0; e < 4; e++) {
                float v = th[j][e] + bt[ci + e] * LOG2E;
                h[e] = f2bf(v);
                l[e] = f2bf(v - bf2f(h[e]));
            }
            uint2 hv, lv;
            hv.x = (unsigned int)h[0] | ((unsigned int)h[1] << 16);
            hv.y = (unsigned int)h[2] | ((unsigned int)h[3] << 16);
            lv.x = (unsigned int)l[0] | ((unsigned int)l[1] << 16);
            lv.y = (unsigned int)l[2] | ((unsigned int)l[3] << 16);
            *(uint2*)&sThH[q * 136 + ci] = hv;
            *(uint2*)&sThL[q * 136 + ci] = lv;
        }
    }
    __syncthreads();
    short8 qh[4], ql[4];
#pragma unroll
    for (int ks = 0; ks < 4; ks++) {
        qh[ks] = *(const short8*)&sThH[(qg * 16 + col) * 136 + ks * 32 + quad * 8];
        ql[ks] = *(const short8*)&sThL[(qg * 16 + col) * 136 + ks * 32 + quad * 8];
    }

    // ---------------- main K-loop
    f32x4 oacc[2];
#pragma unroll
    for (int i = 0; i < 2; i++)
#pragma unroll
        for (int e = 0; e < 4; e++) oacc[i][e] = 0.f;
    float li[4] = { 0.f, 0.f, 0.f, 0.f };

    for (int m0 = 0; m0 < NN; m0 += 64) {
        __syncthreads();   // prev tile LDS reads done; iter 0: qh/ql reads done
        {
            int row = tid >> 4, seg = tid & 15;
            size_t src = ((size_t)(b * NN + m0 + row)) * NCI + seg * 8;
            *(uint4*)&sPhiH[row * 136 + seg * 8] = *(const uint4*)&phiH[src];
            *(uint4*)&sPhiL[row * 136 + seg * 8] = *(const uint4*)&phiL[src];
            int row2 = tid >> 3, seg2 = tid & 7;
            *(uint4*)&sG[row2 * 72 + seg2 * 8] =
                *(const uint4*)&gmat[((size_t)(b * NCI + row2)) * NN + m0 + seg2 * 8];
        }
        __syncthreads();

        // QK: this wave's 16-key quarter
        f32x4 a;
#pragma unroll
        for (int e = 0; e < 4; e++) a[e] = 0.f;
        {
            int kcol = kq * 16 + col;
#pragma unroll
            for (int ks = 0; ks < 4; ks++) {
                short8 ph = *(const short8*)&sPhiH[kcol * 136 + ks * 32 + quad * 8];
                short8 pl = *(const short8*)&sPhiL[kcol * 136 + ks * 32 + quad * 8];
                a = __builtin_amdgcn_mfma_f32_16x16x32_bf16(qh[ks], ph, a, 0, 0, 0);
                a = __builtin_amdgcn_mfma_f32_16x16x32_bf16(qh[ks], pl, a, 0, 0, 0);
                a = __builtin_amdgcn_mfma_f32_16x16x32_bf16(ql[ks], ph, a, 0, 0, 0);
            }
        }
        float pv[4];
#pragma unroll
        for (int r = 0; r < 4; r++) {
            float p = exp2f(a[r]);
            pv[r] = p;
            float rs = p;
#pragma unroll
            for (int off = 1; off < 16; off <<= 1) rs += __shfl_xor(rs, off);
            li[r] += rs;   // partial over this wave's 16 keys
        }
#pragma unroll
        for (int r = 0; r < 4; r++)
            sPall[qg * 1152 + (quad * 4 + r) * 72 + kq * 16 + col] = f2bf(pv[r]);
        __syncthreads();   // all P quarters visible

        // PV: wave (ct2, qt): 32 c x 16 q over 64 keys
        short8 pf[2];
#pragma unroll
        for (int ks = 0; ks < 2; ks++)
            pf[ks] = *(const short8*)&sPall[qt * 1152 + col * 72 + ks * 32 + quad * 8];
#pragma unroll
        for (int i = 0; i < 2; i++)
#pragma unroll
            for (int ks = 0; ks < 2; ks++) {
                short8 af = *(const short8*)&sG[(ct2 * 32 + i * 16 + col) * 72 + ks * 32 + quad * 8];
                oacc[i] = __builtin_amdgcn_mfma_f32_16x16x32_bf16(af, pf[ks], oacc[i], 0, 0, 0);
            }
    }

    // ---------------- merge li across kq quarters (wave index == qg*4+kq)
    if (col == 0) {
#pragma unroll
        for (int r = 0; r < 4; r++) sLi[wave * 16 + quad * 4 + r] = li[r];
    }
    __syncthreads();
    float inv = 1.0f / (sLi[(qt * 4 + 0) * 16 + col] + sLi[(qt * 4 + 1) * 16 + col] +
                        sLi[(qt * 4 + 2) * 16 + col] + sLi[(qt * 4 + 3) * 16 + col]);

    // O -> LDS (bf16), overlays dead sPhiH
    {
        int q = qt * 16 + col;
#pragma unroll
        for (int i = 0; i < 2; i++) {
            int ci = ct2 * 32 + i * 16 + quad * 4;
            uint2 v;
            unsigned short p0 = f2bf(oacc[i][0] * inv);
            unsigned short p1 = f2bf(oacc[i][1] * inv);
            unsigned short p2 = f2bf(oacc[i][2] * inv);
            unsigned short p3 = f2bf(oacc[i][3] * inv);
            v.x = (unsigned int)p0 | ((unsigned int)p1 << 16);
            v.y = (unsigned int)p2 | ((unsigned int)p3 << 16);
            *(uint2*)&sO[q * 136 + ci] = v;
        }
    }
    __syncthreads();
    // stage full Wo [256 o][128 ci] (overlays sG/sPall/sLi — all dead)
#pragma unroll
    for (int i = 0; i < 4; i++) {
        int idx = tid + i * 1024;
        int row = idx >> 4, seg = idx & 15;
        *(uint4*)&sWo[row * 136 + seg * 8] = *(const uint4*)&WoH[(size_t)row * NCI + seg * 8];
    }
    __syncthreads();
    // out-proj: wave's 16-o tile x 4 q-tiles + bias + residual
    f32x4 acc[4];
#pragma unroll
    for (int j = 0; j < 4; j++)
#pragma unroll
        for (int e = 0; e < 4; e++) acc[j][e] = 0.f;
#pragma unroll
    for (int ks = 0; ks < 4; ks++) {
        short8 af = *(const short8*)&sWo[(wave * 16 + col) * 136 + ks * 32 + quad * 8];
#pragma unroll
        for (int j = 0; j < 4; j++) {
            short8 bf = *(const short8*)&sO[(j * 16 + col) * 136 + ks * 32 + quad * 8];
            acc[j] = __builtin_amdgcn_mfma_f32_16x16x32_bf16(af, bf, acc[j], 0, 0, 0);
        }
    }
#pragma unroll
    for (int j = 0; j < 4; j++)
#pragma unroll
        for (int e = 0; e < 4; e++) {
            int o = wave * 16 + quad * 4 + e;
            size_t idx = ((size_t)(b * NC + o)) * NN + n0 + j * 16 + col;
            y[idx] = acc[j][e] + bo[o] + x[idx];
        }
}

// ---------------------------------------------------------------- launch
extern "C" void kernel_launch(void* const* d_in, const int* in_sizes, int n_in,
                              void* d_out, int out_size, void* d_ws, size_t ws_size,
                              hipStream_t stream) {
    float* y = (float*)d_out;

    bool sizes_ok = (n_in == 9) &&
        in_sizes[0] == NB * NC * NN && in_sizes[1] == NCI * NC && in_sizes[2] == NCI &&
        in_sizes[3] == NCI * NC && in_sizes[4] == NCI && in_sizes[5] == NCI * NC &&
        in_sizes[6] == NCI && in_sizes[7] == NC * NCI && in_sizes[8] == NC &&
        out_size == NB * NC * NN;
    if (!sizes_ok) {
        k_fill<<<(out_size + 255) / 256, 256, 0, stream>>>(y, 777.0f, out_size);
        return;
    }
    if (ws_size < (size_t)16 * 1024 * 1024) {
        k_fill<<<(out_size + 255) / 256, 256, 0, stream>>>(y, 555.0f, out_size);
        return;
    }

    const float* x  = (const float*)d_in[0];
    const float* tw = (const float*)d_in[1];
    const float* tb = (const float*)d_in[2];
    const float* pw = (const float*)d_in[3];
    const float* pb = (const float*)d_in[4];
    const float* gw = (const float*)d_in[5];
    const float* gb = (const float*)d_in[6];
    const float* ow = (const float*)d_in[7];
    const float* obias = (const float*)d_in[8];

    unsigned short* ws16 = (unsigned short*)d_ws;
    unsigned short* phiH = ws16;                 // [B][N][Ci] bf16 hi
    unsigned short* phiL = ws16 + 2097152;       // [B][N][Ci] bf16 lo
    unsigned short* g    = ws16 + 4194304;       // [B][Ci][N] bf16
    unsigned short* wbuf = ws16 + 6291456;       // WtH,WtL,WpH,WpL,WgH,WoH
    unsigned short* WtH = wbuf,           *WtL = wbuf + 32768;
    unsigned short* WpH = wbuf + 65536,   *WpL = wbuf + 98304;
    unsigned short* WgH = wbuf + 131072,  *WoH = wbuf + 163840;

    k_split<<<dim3(128, 4), 256, 0, stream>>>(tw, pw, gw, ow, wbuf);
    k_qkv2<<<dim3(128, NB), 256, 0, stream>>>(x, WpH, WpL, WgH, pb, gb, phiH, phiL, g);
    k_attn<<<dim3(256), 1024, 0, stream>>>(x, WtH, WtL, tb, phiH, phiL, g, WoH, obias, y);
}